// Round 5
// baseline (75.890 us; speedup 1.0000x reference)
//
#include <hip/hip_runtime.h>
#include <hip/hip_fp16.h>

#define DIN 256
#define DOUT 128
#define KNBR 32
#define MT 64         // M-tile (rows) per FC block
#define KC 64         // K-chunk (fp32 LDS chunk = 16 KB)

typedef __attribute__((ext_vector_type(4))) float f32x4;
typedef __attribute__((ext_vector_type(8))) short bf16x8;

static __device__ __forceinline__ ushort f2bf(float f) {
    uint u = __float_as_uint(f);
    return (ushort)((u + 0x7FFFu + ((u >> 16) & 1u)) >> 16);   // RNE
}

// packed f32x2 -> bf16x2 (RNE); no builtin on gfx950 -> inline asm
static __device__ __forceinline__ uint cvtpk(float lo, float hi) {
    uint r;
    asm("v_cvt_pk_bf16_f32 %0, %1, %2" : "=v"(r) : "v"(lo), "v"(hi));
    return r;
}

// async global->LDS DMA, 16 B/lane, LDS dest = wave-uniform base + lane*16
static __device__ __forceinline__ void gload_lds16(const float* g, void* l) {
    __builtin_amdgcn_global_load_lds(
        (const __attribute__((address_space(1))) void*)g,
        (__attribute__((address_space(3))) void*)l,
        16, 0, 0);
}

// One-time W fp32 -> bf16 (32768 elems)
__global__ __launch_bounds__(256) void wconv_kernel(
    const float* __restrict__ W, ushort* __restrict__ Wbf)
{
    const int idx = (blockIdx.x * 256 + threadIdx.x) * 4;
    const float4 v = *(const float4*)(W + idx);
    ushort4 o;
    o.x = f2bf(v.x); o.y = f2bf(v.y); o.z = f2bf(v.z); o.w = f2bf(v.w);
    *(ushort4*)(Wbf + idx) = o;
}

// h[n][o] = relu(feats[n][:].W[o][:] + b[o]) via bf16 MFMA, h stored fp16.
// MT=64 rows/block, 4 waves: wave wv computes rows 0..63 x cols wv*32..+31
// (mi 0..3, ni 0..1). A staged fp32 via global_load_lds, double-buffered
// 16 KB chunks (prefetch kc+1 overlaps compute kc). B (64 KB bf16) fully
// preloaded to registers. Source addresses pre-XOR-swizzled (LDS linear).
__global__ __launch_bounds__(256) void fc_mfma_kernel(
    const float* __restrict__ feats, const ushort* __restrict__ Wbf,
    const float* __restrict__ bias, __half* __restrict__ h, int N)
{
    __shared__ float lds_a[2 * MT * KC];   // 2 x 16 KB
    char* lds = (char*)lds_a;

    const int tid  = threadIdx.x;
    const int lane = tid & 63;
    const int wv   = tid >> 6;
    const int l15  = lane & 15, lq = lane >> 4;
    const int nb   = blockIdx.x * MT;

    // ---- stage chunk kc into buffer buf (4 DMA issues/wave, 4 rows each) ----
    auto stage = [&](int kc, int buf) {
        #pragma unroll
        for (int it = 0; it < 4; ++it) {
            const int row = wv * 16 + it * 4 + lq;
            const int c4  = l15 ^ (row & 7);   // pre-swizzled source column
            int grow = nb + row; if (grow > N - 1) grow = N - 1;
            const float* src = feats + (size_t)grow * DIN + kc * KC + c4 * 4;
            gload_lds16(src, lds + buf * (MT * KC * 4) + (wv * 16 + it * 4) * (KC * 4));
        }
    };

    stage(0, 0);   // prologue

    // ---- preload ALL B fragments (whole K): 16 x bf16x8 = 64 VGPR ----
    bf16x8 breg[8][2];
    #pragma unroll
    for (int ks = 0; ks < 8; ++ks)
        #pragma unroll
        for (int ni = 0; ni < 2; ++ni)
            breg[ks][ni] = *(const bf16x8*)(
                Wbf + (size_t)(wv * 32 + ni * 16 + l15) * DIN + ks * 32 + lq * 8);

    f32x4 acc[4][2];
    #pragma unroll
    for (int mi = 0; mi < 4; ++mi)
        #pragma unroll
        for (int ni = 0; ni < 2; ++ni) acc[mi][ni] = (f32x4){0.f, 0.f, 0.f, 0.f};

    #pragma unroll
    for (int kc = 0; kc < DIN / KC; ++kc) {
        __syncthreads();                       // stage(kc) done; prev reads done
        if (kc < DIN / KC - 1) stage(kc + 1, (kc + 1) & 1);
        char* rbuf = lds + (kc & 1) * (MT * KC * 4);

        #pragma unroll
        for (int j = 0; j < 2; ++j) {
            bf16x8 a[4];
            #pragma unroll
            for (int mi = 0; mi < 4; ++mi) {
                const int row = mi * 16 + l15;
                const int X = (row & 7) << 4;
                const int b0 = row * (KC * 4) + j * 128 + lq * 32;
                const f32x4 lo = *(const f32x4*)(rbuf + ((b0) ^ X));
                const f32x4 hi = *(const f32x4*)(rbuf + ((b0 + 16) ^ X));
                uint4 u;
                u.x = cvtpk(lo.x, lo.y); u.y = cvtpk(lo.z, lo.w);
                u.z = cvtpk(hi.x, hi.y); u.w = cvtpk(hi.z, hi.w);
                union { uint4 q; bf16x8 v; } cv; cv.q = u;
                a[mi] = cv.v;
            }
            #pragma unroll
            for (int mi = 0; mi < 4; ++mi)
                #pragma unroll
                for (int ni = 0; ni < 2; ++ni)
                    acc[mi][ni] = __builtin_amdgcn_mfma_f32_16x16x32_bf16(
                        a[mi], breg[kc * 2 + j][ni], acc[mi][ni], 0, 0, 0);
        }
    }

    // ---- epilogue: bias + relu -> fp16 h ----
    float bcol[2];
    #pragma unroll
    for (int ni = 0; ni < 2; ++ni) bcol[ni] = bias[wv * 32 + ni * 16 + l15];

    #pragma unroll
    for (int mi = 0; mi < 4; ++mi) {
        const int rbase = nb + mi * 16 + lq * 4;
        #pragma unroll
        for (int ni = 0; ni < 2; ++ni) {
            const int col = wv * 32 + ni * 16 + l15;
            #pragma unroll
            for (int r = 0; r < 4; ++r) {
                const int n = rbase + r;
                if (n < N) {
                    const float v = fmaxf(acc[mi][ni][r] + bcol[ni], 0.f);
                    h[(size_t)n * DOUT + col] = __float2half_rn(v);
                }
            }
        }
    }
}

// pooled[n][:] = mean_k h[edge[n][k]][:]
// 16 nodes / 256-thr block, 16 lanes per node, 16 B (Half8) per lane.
// 32 fully-unrolled independent gathers per node -> 32 KB in flight per wave.
struct __align__(16) Half8 { __half2 a, b, c, d; };

__global__ __launch_bounds__(256) void pool_kernel(
    const __half* __restrict__ h, const int* __restrict__ edge,
    float* __restrict__ out, int N)
{
    __shared__ int eLds[16 * KNBR];            // 2 KB

    const int tid = threadIdx.x;
    const int g   = tid >> 4;                  // node group 0..15
    const int l   = tid & 15;
    const int nb  = blockIdx.x * 16;

    // stage this block's 512 edge indices (coalesced)
    const int* esrc = edge + (size_t)nb * KNBR;
    eLds[tid]       = esrc[tid];
    eLds[tid + 256] = esrc[tid + 256];
    __syncthreads();

    const Half8* h8 = (const Half8*)h;         // row stride = DOUT/8 = 16
    const int* el = &eLds[g * KNBR];

    float4 acc0 = {0.f, 0.f, 0.f, 0.f};
    float4 acc1 = {0.f, 0.f, 0.f, 0.f};
    #pragma unroll
    for (int k = 0; k < KNBR; ++k) {
        const int idx = el[k];                 // uniform per 16-lane group
        const Half8 v = h8[(size_t)idx * (DOUT / 8) + l];
        const float2 f0 = __half22float2(v.a);
        const float2 f1 = __half22float2(v.b);
        const float2 f2 = __half22float2(v.c);
        const float2 f3 = __half22float2(v.d);
        acc0.x += f0.x; acc0.y += f0.y; acc0.z += f1.x; acc0.w += f1.y;
        acc1.x += f2.x; acc1.y += f2.y; acc1.z += f3.x; acc1.w += f3.y;
    }

    const float s = 1.0f / (float)KNBR;
    float4 r0, r1;
    r0.x = acc0.x * s; r0.y = acc0.y * s; r0.z = acc0.z * s; r0.w = acc0.w * s;
    r1.x = acc1.x * s; r1.y = acc1.y * s; r1.z = acc1.z * s; r1.w = acc1.w * s;

    const int node = nb + g;
    float4* op = (float4*)(out + (size_t)node * DOUT + l * 8);
    op[0] = r0; op[1] = r1;
}

extern "C" void kernel_launch(void* const* d_in, const int* in_sizes, int n_in,
                              void* d_out, int out_size, void* d_ws, size_t ws_size,
                              hipStream_t stream) {
    // dict order: ids, feats, W, b, edge_dict, G, ite
    const float* feats = (const float*)d_in[1];
    const float* W     = (const float*)d_in[2];
    const float* bias  = (const float*)d_in[3];
    const int*   edge  = (const int*)d_in[4];
    float* out = (float*)d_out;

    const int N = in_sizes[1] / DIN;            // 50000
    __half* h   = (__half*)d_ws;                // N*DOUT*2 = 12.8 MB
    ushort* Wbf = (ushort*)((char*)d_ws + (size_t)N * DOUT * sizeof(__half));

    wconv_kernel<<<(DOUT * DIN) / 1024, 256, 0, stream>>>(W, Wbf);
    fc_mfma_kernel<<<(N + MT - 1) / MT, 256, 0, stream>>>(feats, Wbf, bias, h, N);
    pool_kernel<<<N / 16, 256, 0, stream>>>(h, edge, out, N);
}

// Round 6
// 72.863 us; speedup vs baseline: 1.0415x; 1.0415x over previous
//
#include <hip/hip_runtime.h>
#include <hip/hip_fp16.h>

#define DIN 256
#define DOUT 128
#define KNBR 32
#define MT 128        // M-tile (rows) per FC block
#define KC 64         // K-chunk (fp32 LDS = 32 KB)
#define SEGSZ 6250    // pool sort granularity: 8 segments of 6250 rows (1.6 MB)

typedef __attribute__((ext_vector_type(4))) float f32x4;
typedef __attribute__((ext_vector_type(8))) short bf16x8;

static __device__ __forceinline__ ushort f2bf(float f) {
    uint u = __float_as_uint(f);
    return (ushort)((u + 0x7FFFu + ((u >> 16) & 1u)) >> 16);   // RNE
}

// packed f32x2 -> bf16x2 (RNE); no builtin on gfx950 -> inline asm
static __device__ __forceinline__ uint cvtpk(float lo, float hi) {
    uint r;
    asm("v_cvt_pk_bf16_f32 %0, %1, %2" : "=v"(r) : "v"(lo), "v"(hi));
    return r;
}

// async global->LDS DMA, 16 B/lane, LDS dest = wave-uniform base + lane*16
static __device__ __forceinline__ void gload_lds16(const float* g, void* l) {
    __builtin_amdgcn_global_load_lds(
        (const __attribute__((address_space(1))) void*)g,
        (__attribute__((address_space(3))) void*)l,
        16, 0, 0);
}

// One-time W fp32 -> bf16 (32768 elems)
__global__ __launch_bounds__(256) void wconv_kernel(
    const float* __restrict__ W, ushort* __restrict__ Wbf)
{
    const int idx = (blockIdx.x * 256 + threadIdx.x) * 4;
    const float4 v = *(const float4*)(W + idx);
    ushort4 o;
    o.x = f2bf(v.x); o.y = f2bf(v.y); o.z = f2bf(v.z); o.w = f2bf(v.w);
    *(ushort4*)(Wbf + idx) = o;
}

// h[n][o] = relu(feats[n][:].W[o][:] + b[o]) via bf16 MFMA, h stored fp16.
// (round-4 version: MT=128, single-buffered 32 KB chunks, B streamed per chunk)
__global__ __launch_bounds__(256) void fc_mfma_kernel(
    const float* __restrict__ feats, const ushort* __restrict__ Wbf,
    const float* __restrict__ bias, __half* __restrict__ h, int N)
{
    __shared__ float lds_a[MT * KC];   // 32 KB fp32 A-chunk, XOR-swizzled
    char* lds = (char*)lds_a;

    const int tid = threadIdx.x;
    const int lane = tid & 63;
    const int wv  = tid >> 6;
    const int wm  = wv >> 1, wn = wv & 1;
    const int l15 = lane & 15, lq = lane >> 4;
    const int nb  = blockIdx.x * MT;

    f32x4 acc[4][4];
    #pragma unroll
    for (int mi = 0; mi < 4; ++mi)
        #pragma unroll
        for (int ni = 0; ni < 4; ++ni) acc[mi][ni] = (f32x4){0.f, 0.f, 0.f, 0.f};

    #pragma unroll
    for (int kc = 0; kc < DIN / KC; ++kc) {
        if (kc) __syncthreads();   // prior chunk's ds_reads done before overwrite

        // stage A chunk: source pre-swizzled so LDS (linear dest) is swizzled
        #pragma unroll
        for (int it = 0; it < 8; ++it) {
            const int row = wv * 32 + it * 4 + (lane >> 4);
            const int c4  = (lane & 15) ^ (row & 7);
            int grow = nb + row; if (grow > N - 1) grow = N - 1;
            const float* src = feats + (size_t)grow * DIN + kc * KC + c4 * 4;
            gload_lds16(src, lds + (size_t)(wv * 32 + it * 4) * KC * 4);
        }

        // B fragments for this chunk, streamed from L2
        bf16x8 breg[2][4];
        #pragma unroll
        for (int j = 0; j < 2; ++j)
            #pragma unroll
            for (int ni = 0; ni < 4; ++ni)
                breg[j][ni] = *(const bf16x8*)(
                    Wbf + (size_t)(wn * 64 + ni * 16 + l15) * DIN
                        + (kc * 2 + j) * 32 + lq * 8);

        __syncthreads();   // DMA complete

        #pragma unroll
        for (int j = 0; j < 2; ++j) {
            bf16x8 a[4];
            #pragma unroll
            for (int mi = 0; mi < 4; ++mi) {
                const int row = wm * 64 + mi * 16 + l15;
                const int X = (row & 7) << 4;
                const int b0 = row * (KC * 4) + j * 128 + lq * 32;
                const f32x4 lo = *(const f32x4*)(lds + ((b0) ^ X));
                const f32x4 hi = *(const f32x4*)(lds + ((b0 + 16) ^ X));
                uint4 u;
                u.x = cvtpk(lo.x, lo.y); u.y = cvtpk(lo.z, lo.w);
                u.z = cvtpk(hi.x, hi.y); u.w = cvtpk(hi.z, hi.w);
                union { uint4 q; bf16x8 v; } cv; cv.q = u;
                a[mi] = cv.v;
            }
            #pragma unroll
            for (int mi = 0; mi < 4; ++mi)
                #pragma unroll
                for (int ni = 0; ni < 4; ++ni)
                    acc[mi][ni] = __builtin_amdgcn_mfma_f32_16x16x32_bf16(
                        a[mi], breg[j][ni], acc[mi][ni], 0, 0, 0);
        }
    }

    float bcol[4];
    #pragma unroll
    for (int ni = 0; ni < 4; ++ni) bcol[ni] = bias[wn * 64 + ni * 16 + l15];

    #pragma unroll
    for (int mi = 0; mi < 4; ++mi) {
        const int rbase = nb + wm * 64 + mi * 16 + lq * 4;
        #pragma unroll
        for (int ni = 0; ni < 4; ++ni) {
            const int col = wn * 64 + ni * 16 + l15;
            #pragma unroll
            for (int r = 0; r < 4; ++r) {
                const int n = rbase + r;
                if (n < N) {
                    const float v = fmaxf(acc[mi][ni][r] + bcol[ni], 0.f);
                    h[(size_t)n * DOUT + col] = __float2half_rn(v);
                }
            }
        }
    }
}

// pooled[n][:] = mean_k h[edge[n][k]][:]
// 8 nodes / 256-thr block, 32 lanes per node. Counting-sort the 32 neighbor
// indices by 8-segment key (6250 rows = 1.6 MB each), then gather in 8 batches
// of 4 independent loads with a block barrier between batches: sorted order +
// equal-work batches keep co-resident blocks sweeping the same ~2-3 MB h
// window together (L2-resident) while 4 loads/group stay in flight.
struct Half4 { __half2 a, b; };

__global__ __launch_bounds__(256) void pool_kernel(
    const __half* __restrict__ h, const int* __restrict__ edge,
    float* __restrict__ out, int N)
{
    __shared__ int sorted[8 * KNBR];   // 1 KB

    const int lane = threadIdx.x & 63;
    const int grp  = lane >> 5;                 // node sub-group within wave
    const int l31  = lane & 31;
    const int wv   = threadIdx.x >> 6;
    const int nl   = wv * 2 + grp;              // node_local 0..7
    const int node = blockIdx.x * 8 + nl;       // N % 8 == 0

    // ---- load neighbor index (coalesced), counting-sort by 8-way segment ----
    const int myidx = edge[(size_t)node * KNBR + l31];
    const int seg = myidx / SEGSZ;              // 0..7 (magic-mul)

    const unsigned long long f0 = __ballot(seg & 1);
    const unsigned long long f1 = __ballot(seg & 2);
    const unsigned long long f2 = __ballot(seg & 4);
    const uint b0 = grp ? (uint)(f0 >> 32) : (uint)f0;
    const uint b1 = grp ? (uint)(f1 >> 32) : (uint)f1;
    const uint b2 = grp ? (uint)(f2 >> 32) : (uint)f2;

    uint mseg = 0;
    int off = 0;
    #pragma unroll
    for (int t = 0; t < 8; ++t) {
        const uint mt = ((t & 1) ? b0 : ~b0) & ((t & 2) ? b1 : ~b1)
                      & ((t & 4) ? b2 : ~b2);
        if (t == seg) mseg = mt;
        off += (t < seg) ? __popc(mt) : 0;
    }
    const int rank = __popc(mseg & ((1u << l31) - 1));
    sorted[nl * KNBR + off + rank] = myidx;
    __syncthreads();

    // ---- gather-mean: 8 batches x 4 independent loads, barrier-paced ----
    const Half4* h4 = (const Half4*)h;          // row stride = DOUT/4 = 32
    const int* sl = &sorted[nl * KNBR];

    float4 acc = {0.f, 0.f, 0.f, 0.f};
    #pragma unroll
    for (int b = 0; b < 8; ++b) {
        if (b) __syncthreads();                 // pace the segment sweep
        #pragma unroll
        for (int kk = 0; kk < 4; ++kk) {
            const int idxk = sl[b * 4 + kk];    // uniform per group
            const Half4 v = h4[(size_t)idxk * (DOUT / 4) + l31];
            const float2 fa = __half22float2(v.a);
            const float2 fb = __half22float2(v.b);
            acc.x += fa.x; acc.y += fa.y; acc.z += fb.x; acc.w += fb.y;
        }
    }

    const float sc = 1.0f / (float)KNBR;
    float4 r;
    r.x = acc.x * sc; r.y = acc.y * sc; r.z = acc.z * sc; r.w = acc.w * sc;
    ((float4*)out)[(size_t)node * (DOUT / 4) + l31] = r;
}

extern "C" void kernel_launch(void* const* d_in, const int* in_sizes, int n_in,
                              void* d_out, int out_size, void* d_ws, size_t ws_size,
                              hipStream_t stream) {
    // dict order: ids, feats, W, b, edge_dict, G, ite
    const float* feats = (const float*)d_in[1];
    const float* W     = (const float*)d_in[2];
    const float* bias  = (const float*)d_in[3];
    const int*   edge  = (const int*)d_in[4];
    float* out = (float*)d_out;

    const int N = in_sizes[1] / DIN;            // 50000
    __half* h   = (__half*)d_ws;                // N*DOUT*2 = 12.8 MB
    ushort* Wbf = (ushort*)((char*)d_ws + (size_t)N * DOUT * sizeof(__half));

    wconv_kernel<<<(DOUT * DIN) / 1024, 256, 0, stream>>>(W, Wbf);
    fc_mfma_kernel<<<(N + MT - 1) / MT, 256, 0, stream>>>(feats, Wbf, bias, h, N);
    pool_kernel<<<N / 8, 256, 0, stream>>>(h, edge, out, N);
}